// Round 1
// baseline (200.017 us; speedup 1.0000x reference)
//
#include <hip/hip_runtime.h>
#include <hip/hip_bf16.h>

// ChebyKANLinear: y[b,j] = sum_i sum_k T_k(tanh(x[b,i])) * C[i,j,k]
//   x: (16384, 512) f32; C: (512, 512, 9) f32; y: (16384, 512) f32
// Strategy: bf16 MFMA GEMM with contraction axis kflat = k*512 + i.
//   - W packed in d_ws: W[j][k*512+i] = bf16(C[i][j][k])  (512 x 4608 bf16, 4.7MB)
//   - A operand (Chebyshev basis) generated in registers via recurrence, no LDS.

typedef __bf16 bf16x8 __attribute__((ext_vector_type(8)));
typedef float  f32x4  __attribute__((ext_vector_type(4)));

#define DIM  512
#define KDEG 9
#define KF   (DIM * KDEG)   // 4608

// ---------------- pack kernel: C[i][j][k] -> W[j][k*512 + i] (bf16) -------------
__global__ void pack_w_kernel(const float* __restrict__ coeffs,
                              __bf16* __restrict__ W) {
    int tid = blockIdx.x * blockDim.x + threadIdx.x;   // 512*512 threads
    int i = tid & (DIM - 1);
    int j = tid >> 9;
    const float* src = coeffs + ((size_t)i * DIM + j) * KDEG;  // contiguous 9 floats
    __bf16* dst = W + (size_t)j * KF + i;
#pragma unroll
    for (int k = 0; k < KDEG; ++k) {
        dst[k * DIM] = (__bf16)src[k];   // writes: lanes (consecutive i) contiguous
    }
}

// ---------------- fused Chebyshev-basis + MFMA GEMM -----------------------------
// Block: 512 threads = 8 waves as 2(row)x4(col); tile BM=128 x BN=256.
// Wave tile 64x64 of output: 4 m-frags x 4 n-frags of 16x16, K=32 MFMA.
__global__ __launch_bounds__(512, 2) void cheby_gemm_kernel(
    const float* __restrict__ x,
    const __bf16* __restrict__ W,
    float* __restrict__ out)
{
    const int lane = threadIdx.x & 63;
    const int wid  = threadIdx.x >> 6;   // 0..7
    const int wr   = wid >> 2;           // 0..1  (row group of 64)
    const int wc   = wid & 3;            // 0..3  (col group of 64)
    const int bm   = blockIdx.y * 128;
    const int bn   = blockIdx.x * 256;

    const int l15 = lane & 15;
    const int l4  = lane >> 4;           // 0..3  (k-block within MFMA)

    f32x4 acc[4][4] = {};                // 64 VGPRs accumulator

    const float* xrow[4];
#pragma unroll
    for (int mf = 0; mf < 4; ++mf)
        xrow[mf] = x + (size_t)(bm + wr * 64 + mf * 16 + l15) * DIM;

    const __bf16* wcol[4];
#pragma unroll
    for (int nf = 0; nf < 4; ++nf)
        wcol[nf] = W + (size_t)(bn + wc * 64 + nf * 16 + l15) * KF;

    // loop over 16 i-chunks of 32
    for (int ic = 0; ic < 16; ++ic) {
        const int ioff = ic * 32 + l4 * 8;   // this lane's 8 consecutive i's

        float t2[4][8], Tk[4][8], Tm[4][8];
        // load x fragments, compute t = tanh(x) = 1 - 2/(exp(2x)+1)
#pragma unroll
        for (int mf = 0; mf < 4; ++mf) {
            f32x4 x0 = *reinterpret_cast<const f32x4*>(xrow[mf] + ioff);
            f32x4 x1 = *reinterpret_cast<const f32x4*>(xrow[mf] + ioff + 4);
#pragma unroll
            for (int e = 0; e < 8; ++e) {
                float xv = (e < 4) ? x0[e] : x1[e - 4];
                // exp(2x) = exp2(x * 2*log2(e)); saturates to +-1 correctly
                float p  = __builtin_amdgcn_exp2f(xv * 2.8853900817779268f);
                float t  = 1.0f - 2.0f * __builtin_amdgcn_rcpf(p + 1.0f);
                Tk[mf][e] = t;         // T_1
                t2[mf][e] = t + t;
                Tm[mf][e] = 1.0f;      // T_0
            }
        }

        // k = 0: A == 1.0 everywhere (T_0)
        {
            bf16x8 aone;
#pragma unroll
            for (int e = 0; e < 8; ++e) aone[e] = (__bf16)1.0f;
#pragma unroll
            for (int nf = 0; nf < 4; ++nf) {
                bf16x8 b = *reinterpret_cast<const bf16x8*>(
                    wcol[nf] + 0 * DIM + ic * 32 + l4 * 8);
#pragma unroll
                for (int mf = 0; mf < 4; ++mf)
                    acc[mf][nf] = __builtin_amdgcn_mfma_f32_16x16x32_bf16(
                        aone, b, acc[mf][nf], 0, 0, 0);
            }
        }

        // k = 1..8: convert T_k to bf16 frags, MFMA, advance recurrence
#pragma unroll
        for (int k = 1; k < KDEG; ++k) {
            bf16x8 afr[4];
#pragma unroll
            for (int mf = 0; mf < 4; ++mf)
#pragma unroll
                for (int e = 0; e < 8; ++e)
                    afr[mf][e] = (__bf16)Tk[mf][e];

#pragma unroll
            for (int nf = 0; nf < 4; ++nf) {
                bf16x8 b = *reinterpret_cast<const bf16x8*>(
                    wcol[nf] + k * DIM + ic * 32 + l4 * 8);
#pragma unroll
                for (int mf = 0; mf < 4; ++mf)
                    acc[mf][nf] = __builtin_amdgcn_mfma_f32_16x16x32_bf16(
                        afr[mf], b, acc[mf][nf], 0, 0, 0);
            }

            if (k < KDEG - 1) {
#pragma unroll
                for (int mf = 0; mf < 4; ++mf)
#pragma unroll
                    for (int e = 0; e < 8; ++e) {
                        float Tn = __builtin_fmaf(t2[mf][e], Tk[mf][e], -Tm[mf][e]);
                        Tm[mf][e] = Tk[mf][e];
                        Tk[mf][e] = Tn;
                    }
            }
        }
    }

    // epilogue: C/D layout (verified m89): col = lane&15, row = (lane>>4)*4 + r
#pragma unroll
    for (int mf = 0; mf < 4; ++mf)
#pragma unroll
        for (int nf = 0; nf < 4; ++nf)
#pragma unroll
            for (int r = 0; r < 4; ++r) {
                int row = bm + wr * 64 + mf * 16 + l4 * 4 + r;
                int col = bn + wc * 64 + nf * 16 + l15;
                out[(size_t)row * DIM + col] = acc[mf][nf][r];
            }
}

extern "C" void kernel_launch(void* const* d_in, const int* in_sizes, int n_in,
                              void* d_out, int out_size, void* d_ws, size_t ws_size,
                              hipStream_t stream) {
    const float* x      = (const float*)d_in[0];   // (16384, 512)
    const float* coeffs = (const float*)d_in[1];   // (512, 512, 9)
    float* out          = (float*)d_out;           // (16384, 512)
    __bf16* W           = (__bf16*)d_ws;           // 512*4608 bf16 = 4.7MB

    // pack W: 512*512 threads, each handles 9 k's
    pack_w_kernel<<<(DIM * DIM) / 256, 256, 0, stream>>>(coeffs, W);

    // GEMM: grid = (N/256, M/128) = (2, 128) = 256 blocks = 1 per CU
    cheby_gemm_kernel<<<dim3(2, 128), 512, 0, stream>>>(x, W, out);
}